// Round 12
// baseline (145.533 us; speedup 1.0000x reference)
//
#include <hip/hip_runtime.h>
#include <math.h>

#define NCAM 6
#define FHh 16
#define FWw 44
#define PIX 704            // FHh*FWw
#define FCc 128
#define DB 48
#define C3 177             // DB + 1 + 128
#define C3PAD 192
#define KCONV 1152         // FCc*9
#define NG 4224            // NCAM*PIX
#define BEVN 10000
#define CHUNK 2048

// ---- ws layout (float offsets) ----
#define OFF_WT1    0                           // bf16 hi[147456] + lo[147456] (ushort)
#define OFF_WT2    147456                      // same
#define OFF_WT3    294912                      // bf16 hi/lo [192][128] (ushort, 24576 each)
#define OFF_GEO    319488                      // [6*48*704][2] (x,y only)
#define OFF_X1     724992                      // [6][128][704]
#define OFF_X2     1265664
#define OFF_X3     1806336                     // [6][177][704]
#define OFF_PRM    2553984                     // float4 [NG]: py,px,qc,qa
#define OFF_PRM2   2570880                     // float2 [NG]: qb,op
#define OFF_FEATT  2579328                     // [NG][128]
#define OFF_PART   3120000                     // [4][6][128][704] gemm partials
// end = 5,282,688 floats = 20.2 MiB

typedef __attribute__((ext_vector_type(8))) short bf16x8;
typedef __attribute__((ext_vector_type(4))) float f32x4;
typedef __attribute__((ext_vector_type(4))) int i32x4;

__device__ __forceinline__ unsigned short f2bf(float x) {
  unsigned u = __float_as_uint(x);
  return (unsigned short)((u + 0x7FFF + ((u >> 16) & 1)) >> 16);
}
__device__ __forceinline__ float bf2f(unsigned short h) {
  return __uint_as_float(((unsigned)h) << 16);
}

__device__ __forceinline__ void inv3(const float* A, float* I) {
  float a=A[0],b=A[1],c=A[2],d=A[3],e=A[4],f=A[5],g=A[6],h=A[7],i=A[8];
  float c0 = e*i - f*h, c1 = f*g - d*i, c2 = d*h - e*g;
  float det = a*c0 + b*c1 + c*c2;
  float id = 1.f/det;
  I[0]=c0*id; I[1]=(c*h-b*i)*id; I[2]=(b*f-c*e)*id;
  I[3]=c1*id; I[4]=(a*i-c*g)*id; I[5]=(c*d-a*f)*id;
  I[6]=c2*id; I[7]=(b*g-a*h)*id; I[8]=(a*e-b*d)*id;
}

// fused prep + geometry
__global__ void k_geom(const float* __restrict__ rot, const float* __restrict__ intr,
                       const float* __restrict__ post_rot,
                       const float* __restrict__ trans, const float* __restrict__ post_trans,
                       float* __restrict__ ws) {
  __shared__ float sm[NCAM][24];
  if (threadIdx.x < NCAM) {
    int n = threadIdx.x;
    float ip[9], ii[9];
    inv3(post_rot + n*9, ip);
    inv3(intr + n*9, ii);
    const float* R = rot + n*9;
    for (int j = 0; j < 9; ++j) sm[n][j] = ip[j];
    for (int r = 0; r < 3; ++r)
      for (int c = 0; c < 3; ++c) {
        float s = 0.f;
        for (int k = 0; k < 3; ++k) s += R[r*3+k]*ii[k*3+c];
        sm[n][9 + r*3 + c] = s;
      }
  }
  __syncthreads();
  int idx = blockIdx.x*256 + threadIdx.x;
  if (idx >= NCAM*DB*PIX) return;
  int n = idx / (DB*PIX);
  int rem = idx % (DB*PIX);
  int d = rem / PIX;
  int hw = rem % PIX;
  int h = hw / FWw, w = hw % FWw;
  float fx = w * (351.0f/43.0f);
  float fy = h * (127.0f/15.0f);
  float fz = 1.0f + (float)d;
  const float* pt = post_trans + n*3;
  float v0 = fx - pt[0], v1 = fy - pt[1], v2 = fz - pt[2];
  const float* m = sm[n];
  float x = m[0]*v0 + m[1]*v1 + m[2]*v2;
  float y = m[3]*v0 + m[4]*v1 + m[5]*v2;
  float z = m[6]*v0 + m[7]*v1 + m[8]*v2;
  float q0 = x*z, q1 = y*z, q2 = z;
  const float* c = m + 9;
  const float* t = trans + n*3;
  float gx = c[0]*q0 + c[1]*q1 + c[2]*q2 + t[0];
  float gy = c[3]*q0 + c[4]*q1 + c[5]*q2 + t[1];
  ((float2*)(ws + OFF_GEO))[idx] = make_float2(gx, gy);
}

// all weights -> bf16 hi/lo split, layout [oc][k]
__global__ void k_wtrans(const float* __restrict__ w1, const float* __restrict__ w2,
                         const float* __restrict__ w3, float* __restrict__ ws) {
  int e = blockIdx.x*256 + threadIdx.x;
  if (e < 147456) {
    float v1 = w1[e], v2 = w2[e];
    unsigned short h1 = f2bf(v1), h2 = f2bf(v2);
    unsigned short l1 = f2bf(v1 - bf2f(h1)), l2 = f2bf(v2 - bf2f(h2));
    unsigned short* wt1 = (unsigned short*)(ws + OFF_WT1);
    unsigned short* wt2 = (unsigned short*)(ws + OFF_WT2);
    wt1[e] = h1; wt1[147456 + e] = l1;
    wt2[e] = h2; wt2[147456 + e] = l2;
  }
  if (e < 192*128) {                     // conv3: [oc<192][k<128], zero-pad oc>=177
    int oc = e >> 7, k = e & 127;
    float v = (oc < C3) ? w3[oc*FCc + k] : 0.f;
    unsigned short h = f2bf(v);
    unsigned short* wt3 = (unsigned short*)(ws + OFF_WT3);
    wt3[e] = h; wt3[24576 + e] = f2bf(v - bf2f(h));
  }
}

#define LROW 20   // dwords per LDS row: 32 bf16 = 16 dw + 4 pad

// bf16x3 MFMA im2col GEMM, 3x3 convs. Block 256 thr = 4 waves, 64oc x 64px,
// Kchunk 288 (9 steps of K=32). D = AhBh + AhBl + AlBh.
__global__ __launch_bounds__(256) void k_gemm_mfma(
    const float* __restrict__ in, const float* ws, float* __restrict__ part, int woff)
{
  __shared__ int alds[2][64*LROW];
  __shared__ int blds[2][64*LROW];
  int tid = threadIdx.x;
  int px0 = blockIdx.x * 64;
  int oc0 = blockIdx.y * 64;
  int z = blockIdx.z; int n = z >> 2, ks = z & 3;
  const unsigned short* whi = (const unsigned short*)(ws + woff);
  const unsigned short* wlo = whi + 147456;
  const float* inn = in + (size_t)n*FCc*PIX;
  int wv = tid >> 6, lane = tid & 63;
  int a_oc = tid >> 2, a_kq = tid & 3;
  int b_px = tid & 63, b_kq = tid >> 6;
  int p = px0 + b_px; int b_y = p / FWw, b_x = p - b_y*FWw;
  int k00 = ks * 288;

  i32x4 pa_h, pa_l; float bv[8];
  auto issueA = [&](int s) {
    size_t gi = (size_t)(oc0 + a_oc)*KCONV + (k00 + s*32 + a_kq*8);
    pa_h = *(const i32x4*)(whi + gi);
    pa_l = *(const i32x4*)(wlo + gi);
  };
  auto issueB = [&](int s) {
    #pragma unroll
    for (int j = 0; j < 8; ++j) {
      int k = k00 + s*32 + b_kq*8 + j;
      int ic = k / 9, tap = k - ic*9;
      int ky = tap / 3, kx = tap - ky*3;
      int yy = b_y + ky - 1, xx = b_x + kx - 1;
      float v = 0.f;
      if ((unsigned)yy < FHh && (unsigned)xx < FWw) v = inn[(size_t)ic*PIX + yy*FWw + xx];
      bv[j] = v;
    }
  };

  f32x4 a00 = {0.f,0.f,0.f,0.f}, a01 = a00, a10 = a00, a11 = a00;
  int ocr = (wv >> 1) * 32, pxr = (wv & 1) * 32;
  int dq = (lane >> 4) * 4;
  int rA0 = (ocr + (lane & 15)) * LROW + dq;
  int rA1 = rA0 + 16*LROW;
  int rB0 = (pxr + (lane & 15)) * LROW + dq;
  int rB1 = rB0 + 16*LROW;
  int aw = a_oc*LROW + a_kq*4;
  int bw = b_px*LROW + b_kq*4;

  issueA(0); issueB(0);
  for (int s = 0; s < 9; ++s) {
    __syncthreads();
    *(i32x4*)&alds[0][aw] = pa_h;
    *(i32x4*)&alds[1][aw] = pa_l;
    {
      i32x4 vh, vl;
      int th[8], tl[8];
      #pragma unroll
      for (int j = 0; j < 8; ++j) {
        unsigned short h = f2bf(bv[j]);
        th[j] = h; tl[j] = f2bf(bv[j] - bf2f(h));
      }
      vh.x = th[0]|(th[1]<<16); vh.y = th[2]|(th[3]<<16);
      vh.z = th[4]|(th[5]<<16); vh.w = th[6]|(th[7]<<16);
      vl.x = tl[0]|(tl[1]<<16); vl.y = tl[2]|(tl[3]<<16);
      vl.z = tl[4]|(tl[5]<<16); vl.w = tl[6]|(tl[7]<<16);
      *(i32x4*)&blds[0][bw] = vh;
      *(i32x4*)&blds[1][bw] = vl;
    }
    __syncthreads();
    if (s < 8) { issueA(s+1); issueB(s+1); }
    bf16x8 ah0 = *(bf16x8*)&alds[0][rA0], ah1 = *(bf16x8*)&alds[0][rA1];
    bf16x8 al0 = *(bf16x8*)&alds[1][rA0], al1 = *(bf16x8*)&alds[1][rA1];
    bf16x8 bh0 = *(bf16x8*)&blds[0][rB0], bh1 = *(bf16x8*)&blds[0][rB1];
    bf16x8 bl0 = *(bf16x8*)&blds[1][rB0], bl1 = *(bf16x8*)&blds[1][rB1];
    a00 = __builtin_amdgcn_mfma_f32_16x16x32_bf16(ah0, bh0, a00, 0, 0, 0);
    a01 = __builtin_amdgcn_mfma_f32_16x16x32_bf16(ah0, bh1, a01, 0, 0, 0);
    a10 = __builtin_amdgcn_mfma_f32_16x16x32_bf16(ah1, bh0, a10, 0, 0, 0);
    a11 = __builtin_amdgcn_mfma_f32_16x16x32_bf16(ah1, bh1, a11, 0, 0, 0);
    a00 = __builtin_amdgcn_mfma_f32_16x16x32_bf16(ah0, bl0, a00, 0, 0, 0);
    a01 = __builtin_amdgcn_mfma_f32_16x16x32_bf16(ah0, bl1, a01, 0, 0, 0);
    a10 = __builtin_amdgcn_mfma_f32_16x16x32_bf16(ah1, bl0, a10, 0, 0, 0);
    a11 = __builtin_amdgcn_mfma_f32_16x16x32_bf16(ah1, bl1, a11, 0, 0, 0);
    a00 = __builtin_amdgcn_mfma_f32_16x16x32_bf16(al0, bh0, a00, 0, 0, 0);
    a01 = __builtin_amdgcn_mfma_f32_16x16x32_bf16(al0, bh1, a01, 0, 0, 0);
    a10 = __builtin_amdgcn_mfma_f32_16x16x32_bf16(al1, bh0, a10, 0, 0, 0);
    a11 = __builtin_amdgcn_mfma_f32_16x16x32_bf16(al1, bh1, a11, 0, 0, 0);
  }
  float* pp = part + (size_t)(ks*NCAM + n)*FCc*PIX;
  int ocb = oc0 + ocr + ((lane >> 4) << 2);
  int pxb = px0 + pxr + (lane & 15);
  #pragma unroll
  for (int i = 0; i < 4; ++i) {
    pp[(size_t)(ocb + i)*PIX + pxb]           = a00[i];
    pp[(size_t)(ocb + i)*PIX + pxb + 16]      = a01[i];
    pp[(size_t)(ocb + 16 + i)*PIX + pxb]      = a10[i];
    pp[(size_t)(ocb + 16 + i)*PIX + pxb + 16] = a11[i];
  }
}

// bf16x3 MFMA GEMM for conv3 (1x1, K=128, bias fused, direct X3 write).
__global__ __launch_bounds__(256) void k_gemm_mfma3(
    const float* __restrict__ in, const float* ws,
    const float* __restrict__ bias, float* __restrict__ outbuf)
{
  __shared__ int alds[2][64*LROW];
  __shared__ int blds[2][64*LROW];
  int tid = threadIdx.x;
  int px0 = blockIdx.x * 64;
  int oc0 = blockIdx.y * 64;
  int n = blockIdx.z;
  const unsigned short* whi = (const unsigned short*)(ws + OFF_WT3);
  const unsigned short* wlo = whi + 24576;
  const float* inn = in + (size_t)n*FCc*PIX;
  int wv = tid >> 6, lane = tid & 63;
  int a_oc = tid >> 2, a_kq = tid & 3;
  int b_px = tid & 63, b_kq = tid >> 6;
  int p = px0 + b_px;

  i32x4 pa_h, pa_l; float bvv[8];
  auto issueA = [&](int s) {
    size_t gi = (size_t)(oc0 + a_oc)*128 + (s*32 + a_kq*8);
    pa_h = *(const i32x4*)(whi + gi);
    pa_l = *(const i32x4*)(wlo + gi);
  };
  auto issueB = [&](int s) {
    #pragma unroll
    for (int j = 0; j < 8; ++j) {
      int ic = s*32 + b_kq*8 + j;
      bvv[j] = inn[(size_t)ic*PIX + p];
    }
  };

  f32x4 a00 = {0.f,0.f,0.f,0.f}, a01 = a00, a10 = a00, a11 = a00;
  int ocr = (wv >> 1) * 32, pxr = (wv & 1) * 32;
  int dq = (lane >> 4) * 4;
  int rA0 = (ocr + (lane & 15)) * LROW + dq;
  int rA1 = rA0 + 16*LROW;
  int rB0 = (pxr + (lane & 15)) * LROW + dq;
  int rB1 = rB0 + 16*LROW;
  int aw = a_oc*LROW + a_kq*4;
  int bw = b_px*LROW + b_kq*4;

  issueA(0); issueB(0);
  for (int s = 0; s < 4; ++s) {
    __syncthreads();
    *(i32x4*)&alds[0][aw] = pa_h;
    *(i32x4*)&alds[1][aw] = pa_l;
    {
      i32x4 vh, vl;
      int th[8], tl[8];
      #pragma unroll
      for (int j = 0; j < 8; ++j) {
        unsigned short h = f2bf(bvv[j]);
        th[j] = h; tl[j] = f2bf(bvv[j] - bf2f(h));
      }
      vh.x = th[0]|(th[1]<<16); vh.y = th[2]|(th[3]<<16);
      vh.z = th[4]|(th[5]<<16); vh.w = th[6]|(th[7]<<16);
      vl.x = tl[0]|(tl[1]<<16); vl.y = tl[2]|(tl[3]<<16);
      vl.z = tl[4]|(tl[5]<<16); vl.w = tl[6]|(tl[7]<<16);
      *(i32x4*)&blds[0][bw] = vh;
      *(i32x4*)&blds[1][bw] = vl;
    }
    __syncthreads();
    if (s < 3) { issueA(s+1); issueB(s+1); }
    bf16x8 ah0 = *(bf16x8*)&alds[0][rA0], ah1 = *(bf16x8*)&alds[0][rA1];
    bf16x8 al0 = *(bf16x8*)&alds[1][rA0], al1 = *(bf16x8*)&alds[1][rA1];
    bf16x8 bh0 = *(bf16x8*)&blds[0][rB0], bh1 = *(bf16x8*)&blds[0][rB1];
    bf16x8 bl0 = *(bf16x8*)&blds[1][rB0], bl1 = *(bf16x8*)&blds[1][rB1];
    a00 = __builtin_amdgcn_mfma_f32_16x16x32_bf16(ah0, bh0, a00, 0, 0, 0);
    a01 = __builtin_amdgcn_mfma_f32_16x16x32_bf16(ah0, bh1, a01, 0, 0, 0);
    a10 = __builtin_amdgcn_mfma_f32_16x16x32_bf16(ah1, bh0, a10, 0, 0, 0);
    a11 = __builtin_amdgcn_mfma_f32_16x16x32_bf16(ah1, bh1, a11, 0, 0, 0);
    a00 = __builtin_amdgcn_mfma_f32_16x16x32_bf16(ah0, bl0, a00, 0, 0, 0);
    a01 = __builtin_amdgcn_mfma_f32_16x16x32_bf16(ah0, bl1, a01, 0, 0, 0);
    a10 = __builtin_amdgcn_mfma_f32_16x16x32_bf16(ah1, bl0, a10, 0, 0, 0);
    a11 = __builtin_amdgcn_mfma_f32_16x16x32_bf16(ah1, bl1, a11, 0, 0, 0);
    a00 = __builtin_amdgcn_mfma_f32_16x16x32_bf16(al0, bh0, a00, 0, 0, 0);
    a01 = __builtin_amdgcn_mfma_f32_16x16x32_bf16(al0, bh1, a01, 0, 0, 0);
    a10 = __builtin_amdgcn_mfma_f32_16x16x32_bf16(al1, bh0, a10, 0, 0, 0);
    a11 = __builtin_amdgcn_mfma_f32_16x16x32_bf16(al1, bh1, a11, 0, 0, 0);
  }
  int ocb = oc0 + ocr + ((lane >> 4) << 2);
  int pxb = px0 + pxr + (lane & 15);
  #pragma unroll
  for (int i = 0; i < 4; ++i) {
    int o0 = ocb + i, o1 = ocb + 16 + i;
    if (o0 < C3) {
      float b = bias[o0];
      outbuf[(size_t)(n*C3 + o0)*PIX + pxb]      = a00[i] + b;
      outbuf[(size_t)(n*C3 + o0)*PIX + pxb + 16] = a01[i] + b;
    }
    if (o1 < C3) {
      float b = bias[o1];
      outbuf[(size_t)(n*C3 + o1)*PIX + pxb]      = a10[i] + b;
      outbuf[(size_t)(n*C3 + o1)*PIX + pxb + 16] = a11[i] + b;
    }
  }
}

__global__ void k_epi_bn(const float* __restrict__ part, const float* __restrict__ cb,
                         const float* __restrict__ g, const float* __restrict__ be,
                         const float* __restrict__ mn, const float* __restrict__ vr,
                         float* __restrict__ out, int KSPLIT)
{
  int idx = blockIdx.x*256 + threadIdx.x;
  if (idx >= NCAM*FCc*176) return;
  int px4 = idx % 176;
  int t = idx / 176;
  int oc = t % FCc;
  int n = t / FCc;
  float4 s = {0.f,0.f,0.f,0.f};
  for (int ks = 0; ks < KSPLIT; ++ks) {
    const float4* p = (const float4*)(part + (size_t)((ks*NCAM+n)*FCc + oc)*PIX);
    float4 v = p[px4];
    s.x += v.x; s.y += v.y; s.z += v.z; s.w += v.w;
  }
  float inv = g[oc] * rsqrtf(vr[oc] + 1e-3f);
  float sh = (cb[oc] - mn[oc]) * inv + be[oc];
  float4 o;
  o.x = fmaxf(s.x*inv + sh, 0.f);
  o.y = fmaxf(s.y*inv + sh, 0.f);
  o.z = fmaxf(s.z*inv + sh, 0.f);
  o.w = fmaxf(s.w*inv + sh, 0.f);
  ((float4*)(out + (size_t)(n*FCc + oc)*PIX))[px4] = o;
}

__global__ void k_moments(float* __restrict__ ws) {
  int wid  = (blockIdx.x * 256 + threadIdx.x) >> 6;
  int lane = threadIdx.x & 63;
  int n = wid / PIX, hw = wid % PIX;
  const float* x3 = ws + OFF_X3 + (size_t)n*C3*PIX + hw;
  float logit = (lane < DB) ? x3[(size_t)lane*PIX] : -1e30f;
  float mx = logit;
  for (int off = 1; off < 64; off <<= 1) mx = fmaxf(mx, __shfl_xor(mx, off));
  float e = (lane < DB) ? expf(logit - mx) : 0.f;
  float s = e;
  for (int off = 1; off < 64; off <<= 1) s += __shfl_xor(s, off);
  float p = e / s;
  float gx = 0.f, gy = 0.f;
  if (lane < DB) {
    float2 g2 = ((const float2*)(ws + OFF_GEO))[(size_t)(n*DB + lane)*PIX + hw];
    gx = g2.x; gy = g2.y;
  }
  float sx = p*gx;
  for (int off = 1; off < 64; off <<= 1) sx += __shfl_xor(sx, off);
  float sy = p*gy;
  for (int off = 1; off < 64; off <<= 1) sy += __shfl_xor(sy, off);
  float dx = gx - sx, dy = gy - sy;
  float c00 = p*dx*dx, c01 = p*dx*dy, c11 = p*dy*dy;
  for (int off = 1; off < 64; off <<= 1) c00 += __shfl_xor(c00, off);
  for (int off = 1; off < 64; off <<= 1) c01 += __shfl_xor(c01, off);
  for (int off = 1; off < 64; off <<= 1) c11 += __shfl_xor(c11, off);
  float opl = x3[(size_t)DB*PIX];
  float opac = 1.f / (1.f + expf(-opl));
  float a = c11*(1.f/9.f) + 0.3f;
  float b = c01*(1.f/9.f);
  float c = c00*(1.f/9.f) + 0.3f;
  float py = 50.f - sy;
  float px = 50.f - sx;
  float det = a*c - b*b;
  float op = (opac > 0.05f) ? opac : 0.f;
  float invd = 1.f;
  if (det > 0.f) invd = 1.f/det; else op = 0.f;
  if (lane == 0) {
    ((float4*)(ws + OFF_PRM))[wid]  = make_float4(py, px, -0.5f*c*invd, -0.5f*a*invd);
    ((float2*)(ws + OFF_PRM2))[wid] = make_float2(b*invd, op);
  }
  float* ft = ws + OFF_FEATT + (size_t)wid*128;
  ft[lane]      = x3[(size_t)(DB + 1 + lane)*PIX];
  ft[lane + 64] = x3[(size_t)(DB + 1 + lane + 64)*PIX];
}

template<int CTRL, int RMASK>
__device__ __forceinline__ float dpp_mul(float v) {
  int t = __builtin_amdgcn_update_dpp(0x3f800000, __float_as_int(v), CTRL, RMASK, 0xF, false);
  return v * __int_as_float(t);
}

// Dense raster, LDS-staged params (CHUNK=2048, 48KB). LPT block order: grid
// (13 col-strips, 100 rows) remapped serpentine outside-in so edge blocks
// (slowest: no early exit) dispatch first, center blocks fill the tail.
// Dynamic gather batch: popc<=4 -> single 4-wide batch, else 8-wide loop.
__global__ __launch_bounds__(512) void k_raster(const float* __restrict__ ws,
                                                float* __restrict__ out) {
  __shared__ float4 s4[CHUNK];
  __shared__ float2 s2[CHUNK];
  int lane = threadIdx.x & 63, wv = threadIdx.x >> 6;
  int bx = blockIdx.x;                   // 0..12
  int by = blockIdx.y;                   // 0..99
  int sx = (bx & 1) ? 12 - (bx >> 1) : (bx >> 1);
  int r  = (by & 1) ? 99 - (by >> 1) : (by >> 1);
  int col = sx*8 + wv;                   // 0..103
  bool valid = col < 100;
  int pix = r*100 + col;
  float yi = (float)r, xi = (float)col;
  const float4* prm4 = (const float4*)(ws + OFF_PRM);
  const float2* prm2 = (const float2*)(ws + OFF_PRM2);
  const float2* ft = (const float2*)(ws + OFF_FEATT);
  float T = 1.f, ax = 0.f, ay = 0.f;
  bool alive = valid;
  for (int c0 = 0; c0 < NG; c0 += CHUNK) {
    if (__syncthreads_count(alive ? 1 : 0) == 0) break;
    int cn = min(CHUNK, NG - c0);
    for (int i = threadIdx.x; i < cn; i += 512) {
      s4[i] = prm4[c0 + i];
      s2[i] = prm2[c0 + i];
    }
    __syncthreads();
    if (alive) {
      for (int gl = 0; gl < cn; gl += 64) {
        float4 c4 = s4[gl + lane];
        float2 c2 = s2[gl + lane];
        float dyv = c4.x - yi, dxv = c4.y - xi;
        float pw = c4.z*dyv*dyv + c4.w*dxv*dxv + c2.x*dyv*dxv;
        float alpha = c2.y * __expf(fminf(pw, 0.f));
        alpha = fminf(alpha, 0.99f);
        if (alpha < (1.f/255.f)) alpha = 0.f;
        unsigned long long m0 = __ballot(alpha > 0.f);
        if (m0) {
          float P = 1.f - alpha;
          P = dpp_mul<0x111, 0xF>(P);
          P = dpp_mul<0x112, 0xF>(P);
          P = dpp_mul<0x114, 0xF>(P);
          P = dpp_mul<0x118, 0xF>(P);
          P = dpp_mul<0x142, 0xA>(P);
          P = dpp_mul<0x143, 0xC>(P);
          float E = __int_as_float(__builtin_amdgcn_update_dpp(
                      0x3f800000, __float_as_int(P), 0x138, 0xF, 0xF, false));
          float w = alpha * T * E;
          T *= __int_as_float(__builtin_amdgcn_readlane(__float_as_int(P), 63));
          unsigned long long mask = __ballot(w > 1e-9f);
          int g0 = c0 + gl;
          if (mask) {
            int nh = __popcll(mask);
            if (nh <= 4) {               // common case: one 4-wide batch
              int jj[4];
              #pragma unroll
              for (int b = 0; b < 4; ++b) {
                if (mask) { jj[b] = __builtin_ctzll(mask); mask &= mask - 1ull; }
                else jj[b] = -1;
              }
              float2 fb[4]; float wb[4];
              #pragma unroll
              for (int b = 0; b < 4; ++b) {
                int j = (jj[b] >= 0) ? jj[b] : jj[0];
                fb[b] = ft[(size_t)(g0 + j)*64 + lane];
                wb[b] = (jj[b] >= 0)
                  ? __int_as_float(__builtin_amdgcn_readlane(__float_as_int(w), jj[b]))
                  : 0.f;
              }
              #pragma unroll
              for (int b = 0; b < 4; ++b) { ax += wb[b]*fb[b].x; ay += wb[b]*fb[b].y; }
            } else {
              while (mask) {
                int jj[8];
                #pragma unroll
                for (int b = 0; b < 8; ++b) {
                  if (mask) { jj[b] = __builtin_ctzll(mask); mask &= mask - 1ull; }
                  else jj[b] = -1;
                }
                float2 fb[8]; float wb[8];
                #pragma unroll
                for (int b = 0; b < 8; ++b) {
                  int j = (jj[b] >= 0) ? jj[b] : jj[0];
                  fb[b] = ft[(size_t)(g0 + j)*64 + lane];
                  wb[b] = (jj[b] >= 0)
                    ? __int_as_float(__builtin_amdgcn_readlane(__float_as_int(w), jj[b]))
                    : 0.f;
                }
                #pragma unroll
                for (int b = 0; b < 8; ++b) { ax += wb[b]*fb[b].x; ay += wb[b]*fb[b].y; }
              }
            }
          }
          if (T < 1e-7f) { alive = false; break; }
        }
      }
    }
  }
  if (valid) {
    out[(size_t)(2*lane)*BEVN + pix]   = ax;
    out[(size_t)(2*lane+1)*BEVN + pix] = ay;
  }
}

extern "C" void kernel_launch(void* const* d_in, const int* in_sizes, int n_in,
                              void* d_out, int out_size, void* d_ws, size_t ws_size,
                              hipStream_t stream) {
  const float* rot        = (const float*)d_in[0];
  const float* trans      = (const float*)d_in[1];
  const float* intr       = (const float*)d_in[2];
  const float* post_rot   = (const float*)d_in[3];
  const float* post_trans = (const float*)d_in[4];
  const float* img        = (const float*)d_in[5];
  const float* w1  = (const float*)d_in[6];
  const float* b1  = (const float*)d_in[7];
  const float* g1  = (const float*)d_in[8];
  const float* be1 = (const float*)d_in[9];
  const float* m1  = (const float*)d_in[10];
  const float* v1  = (const float*)d_in[11];
  const float* w2  = (const float*)d_in[12];
  const float* b2  = (const float*)d_in[13];
  const float* g2  = (const float*)d_in[14];
  const float* be2 = (const float*)d_in[15];
  const float* m2  = (const float*)d_in[16];
  const float* v2  = (const float*)d_in[17];
  const float* w3  = (const float*)d_in[18];
  const float* b3  = (const float*)d_in[19];
  float* ws  = (float*)d_ws;
  float* out = (float*)d_out;

  k_wtrans<<<576, 256, 0, stream>>>(w1, w2, w3, ws);
  k_geom<<<792, 256, 0, stream>>>(rot, intr, post_rot, trans, post_trans, ws);

  // conv1: bf16x3 MFMA, K=1152, KSPLIT=4
  k_gemm_mfma<<<dim3(11,2,24), 256, 0, stream>>>(img, ws, ws+OFF_PART, OFF_WT1);
  k_epi_bn<<<528, 256, 0, stream>>>(ws+OFF_PART, b1, g1, be1, m1, v1, ws+OFF_X1, 4);
  // conv2
  k_gemm_mfma<<<dim3(11,2,24), 256, 0, stream>>>(ws+OFF_X1, ws, ws+OFF_PART, OFF_WT2);
  k_epi_bn<<<528, 256, 0, stream>>>(ws+OFF_PART, b2, g2, be2, m2, v2, ws+OFF_X2, 4);
  // conv3: 1x1, K=128, bf16x3 MFMA, bias fused, direct X3 write
  k_gemm_mfma3<<<dim3(11,3,6), 256, 0, stream>>>(ws+OFF_X2, ws, b3, ws+OFF_X3);

  k_moments<<<1056, 256, 0, stream>>>(ws);
  k_raster<<<dim3(13,100), 512, 0, stream>>>(ws, out);
}

// Round 13
// 124.526 us; speedup vs baseline: 1.1687x; 1.1687x over previous
//
#include <hip/hip_runtime.h>
#include <math.h>

#define NCAM 6
#define FHh 16
#define FWw 44
#define PIX 704            // FHh*FWw
#define FCc 128
#define DB 48
#define C3 177             // DB + 1 + 128
#define C3PAD 192
#define KCONV 1152         // FCc*9
#define NG 4224            // NCAM*PIX
#define BEVN 10000
#define CHUNK 2048
#define TH_LOG (-5.5412635f)   // -ln(255): alpha>=1/255  <=>  pw+lop >= TH_LOG

// ---- ws layout (float offsets) ----
#define OFF_WT1    0                           // bf16 hi[147456] + lo[147456] (ushort)
#define OFF_WT2    147456                      // same
#define OFF_WT3    294912                      // bf16 hi/lo [192][128] (ushort, 24576 each)
#define OFF_GEO    319488                      // [6*48*704][2] (x,y only)
#define OFF_X1     724992                      // [6][128][704]
#define OFF_X2     1265664
#define OFF_X3     1806336                     // [6][177][704]
#define OFF_PRM    2553984                     // float4 [NG]: py,px,qc,qa
#define OFF_PRM2   2570880                     // float2 [NG]: qb,lop
#define OFF_FEATT  2579328                     // [NG][128]
#define OFF_PART   3120000                     // [4][6][128][704] gemm partials
// end = 5,282,688 floats = 20.2 MiB

typedef __attribute__((ext_vector_type(8))) short bf16x8;
typedef __attribute__((ext_vector_type(4))) float f32x4;
typedef __attribute__((ext_vector_type(4))) int i32x4;

__device__ __forceinline__ unsigned short f2bf(float x) {
  unsigned u = __float_as_uint(x);
  return (unsigned short)((u + 0x7FFF + ((u >> 16) & 1)) >> 16);
}
__device__ __forceinline__ float bf2f(unsigned short h) {
  return __uint_as_float(((unsigned)h) << 16);
}

__device__ __forceinline__ void inv3(const float* A, float* I) {
  float a=A[0],b=A[1],c=A[2],d=A[3],e=A[4],f=A[5],g=A[6],h=A[7],i=A[8];
  float c0 = e*i - f*h, c1 = f*g - d*i, c2 = d*h - e*g;
  float det = a*c0 + b*c1 + c*c2;
  float id = 1.f/det;
  I[0]=c0*id; I[1]=(c*h-b*i)*id; I[2]=(b*f-c*e)*id;
  I[3]=c1*id; I[4]=(a*i-c*g)*id; I[5]=(c*d-a*f)*id;
  I[6]=c2*id; I[7]=(b*g-a*h)*id; I[8]=(a*e-b*d)*id;
}

// fused prep + geometry
__global__ void k_geom(const float* __restrict__ rot, const float* __restrict__ intr,
                       const float* __restrict__ post_rot,
                       const float* __restrict__ trans, const float* __restrict__ post_trans,
                       float* __restrict__ ws) {
  __shared__ float sm[NCAM][24];
  if (threadIdx.x < NCAM) {
    int n = threadIdx.x;
    float ip[9], ii[9];
    inv3(post_rot + n*9, ip);
    inv3(intr + n*9, ii);
    const float* R = rot + n*9;
    for (int j = 0; j < 9; ++j) sm[n][j] = ip[j];
    for (int r = 0; r < 3; ++r)
      for (int c = 0; c < 3; ++c) {
        float s = 0.f;
        for (int k = 0; k < 3; ++k) s += R[r*3+k]*ii[k*3+c];
        sm[n][9 + r*3 + c] = s;
      }
  }
  __syncthreads();
  int idx = blockIdx.x*256 + threadIdx.x;
  if (idx >= NCAM*DB*PIX) return;
  int n = idx / (DB*PIX);
  int rem = idx % (DB*PIX);
  int d = rem / PIX;
  int hw = rem % PIX;
  int h = hw / FWw, w = hw % FWw;
  float fx = w * (351.0f/43.0f);
  float fy = h * (127.0f/15.0f);
  float fz = 1.0f + (float)d;
  const float* pt = post_trans + n*3;
  float v0 = fx - pt[0], v1 = fy - pt[1], v2 = fz - pt[2];
  const float* m = sm[n];
  float x = m[0]*v0 + m[1]*v1 + m[2]*v2;
  float y = m[3]*v0 + m[4]*v1 + m[5]*v2;
  float z = m[6]*v0 + m[7]*v1 + m[8]*v2;
  float q0 = x*z, q1 = y*z, q2 = z;
  const float* c = m + 9;
  const float* t = trans + n*3;
  float gx = c[0]*q0 + c[1]*q1 + c[2]*q2 + t[0];
  float gy = c[3]*q0 + c[4]*q1 + c[5]*q2 + t[1];
  ((float2*)(ws + OFF_GEO))[idx] = make_float2(gx, gy);
}

// all weights -> bf16 hi/lo split, layout [oc][k]
__global__ void k_wtrans(const float* __restrict__ w1, const float* __restrict__ w2,
                         const float* __restrict__ w3, float* __restrict__ ws) {
  int e = blockIdx.x*256 + threadIdx.x;
  if (e < 147456) {
    float v1 = w1[e], v2 = w2[e];
    unsigned short h1 = f2bf(v1), h2 = f2bf(v2);
    unsigned short l1 = f2bf(v1 - bf2f(h1)), l2 = f2bf(v2 - bf2f(h2));
    unsigned short* wt1 = (unsigned short*)(ws + OFF_WT1);
    unsigned short* wt2 = (unsigned short*)(ws + OFF_WT2);
    wt1[e] = h1; wt1[147456 + e] = l1;
    wt2[e] = h2; wt2[147456 + e] = l2;
  }
  if (e < 192*128) {                     // conv3: [oc<192][k<128], zero-pad oc>=177
    int oc = e >> 7, k = e & 127;
    float v = (oc < C3) ? w3[oc*FCc + k] : 0.f;
    unsigned short h = f2bf(v);
    unsigned short* wt3 = (unsigned short*)(ws + OFF_WT3);
    wt3[e] = h; wt3[24576 + e] = f2bf(v - bf2f(h));
  }
}

#define LROW 20   // dwords per LDS row: 32 bf16 = 16 dw + 4 pad

// bf16x3 MFMA im2col GEMM, 3x3 convs. Block 256 thr = 4 waves, 64oc x 64px,
// Kchunk 288 (9 steps of K=32). D = AhBh + AhBl + AlBh.
__global__ __launch_bounds__(256) void k_gemm_mfma(
    const float* __restrict__ in, const float* ws, float* __restrict__ part, int woff)
{
  __shared__ int alds[2][64*LROW];
  __shared__ int blds[2][64*LROW];
  int tid = threadIdx.x;
  int px0 = blockIdx.x * 64;
  int oc0 = blockIdx.y * 64;
  int z = blockIdx.z; int n = z >> 2, ks = z & 3;
  const unsigned short* whi = (const unsigned short*)(ws + woff);
  const unsigned short* wlo = whi + 147456;
  const float* inn = in + (size_t)n*FCc*PIX;
  int wv = tid >> 6, lane = tid & 63;
  int a_oc = tid >> 2, a_kq = tid & 3;
  int b_px = tid & 63, b_kq = tid >> 6;
  int p = px0 + b_px; int b_y = p / FWw, b_x = p - b_y*FWw;
  int k00 = ks * 288;

  i32x4 pa_h, pa_l; float bv[8];
  auto issueA = [&](int s) {
    size_t gi = (size_t)(oc0 + a_oc)*KCONV + (k00 + s*32 + a_kq*8);
    pa_h = *(const i32x4*)(whi + gi);
    pa_l = *(const i32x4*)(wlo + gi);
  };
  auto issueB = [&](int s) {
    #pragma unroll
    for (int j = 0; j < 8; ++j) {
      int k = k00 + s*32 + b_kq*8 + j;
      int ic = k / 9, tap = k - ic*9;
      int ky = tap / 3, kx = tap - ky*3;
      int yy = b_y + ky - 1, xx = b_x + kx - 1;
      float v = 0.f;
      if ((unsigned)yy < FHh && (unsigned)xx < FWw) v = inn[(size_t)ic*PIX + yy*FWw + xx];
      bv[j] = v;
    }
  };

  f32x4 a00 = {0.f,0.f,0.f,0.f}, a01 = a00, a10 = a00, a11 = a00;
  int ocr = (wv >> 1) * 32, pxr = (wv & 1) * 32;
  int dq = (lane >> 4) * 4;
  int rA0 = (ocr + (lane & 15)) * LROW + dq;
  int rA1 = rA0 + 16*LROW;
  int rB0 = (pxr + (lane & 15)) * LROW + dq;
  int rB1 = rB0 + 16*LROW;
  int aw = a_oc*LROW + a_kq*4;
  int bw = b_px*LROW + b_kq*4;

  issueA(0); issueB(0);
  for (int s = 0; s < 9; ++s) {
    __syncthreads();
    *(i32x4*)&alds[0][aw] = pa_h;
    *(i32x4*)&alds[1][aw] = pa_l;
    {
      i32x4 vh, vl;
      int th[8], tl[8];
      #pragma unroll
      for (int j = 0; j < 8; ++j) {
        unsigned short h = f2bf(bv[j]);
        th[j] = h; tl[j] = f2bf(bv[j] - bf2f(h));
      }
      vh.x = th[0]|(th[1]<<16); vh.y = th[2]|(th[3]<<16);
      vh.z = th[4]|(th[5]<<16); vh.w = th[6]|(th[7]<<16);
      vl.x = tl[0]|(tl[1]<<16); vl.y = tl[2]|(tl[3]<<16);
      vl.z = tl[4]|(tl[5]<<16); vl.w = tl[6]|(tl[7]<<16);
      *(i32x4*)&blds[0][bw] = vh;
      *(i32x4*)&blds[1][bw] = vl;
    }
    __syncthreads();
    if (s < 8) { issueA(s+1); issueB(s+1); }
    bf16x8 ah0 = *(bf16x8*)&alds[0][rA0], ah1 = *(bf16x8*)&alds[0][rA1];
    bf16x8 al0 = *(bf16x8*)&alds[1][rA0], al1 = *(bf16x8*)&alds[1][rA1];
    bf16x8 bh0 = *(bf16x8*)&blds[0][rB0], bh1 = *(bf16x8*)&blds[0][rB1];
    bf16x8 bl0 = *(bf16x8*)&blds[1][rB0], bl1 = *(bf16x8*)&blds[1][rB1];
    a00 = __builtin_amdgcn_mfma_f32_16x16x32_bf16(ah0, bh0, a00, 0, 0, 0);
    a01 = __builtin_amdgcn_mfma_f32_16x16x32_bf16(ah0, bh1, a01, 0, 0, 0);
    a10 = __builtin_amdgcn_mfma_f32_16x16x32_bf16(ah1, bh0, a10, 0, 0, 0);
    a11 = __builtin_amdgcn_mfma_f32_16x16x32_bf16(ah1, bh1, a11, 0, 0, 0);
    a00 = __builtin_amdgcn_mfma_f32_16x16x32_bf16(ah0, bl0, a00, 0, 0, 0);
    a01 = __builtin_amdgcn_mfma_f32_16x16x32_bf16(ah0, bl1, a01, 0, 0, 0);
    a10 = __builtin_amdgcn_mfma_f32_16x16x32_bf16(ah1, bl0, a10, 0, 0, 0);
    a11 = __builtin_amdgcn_mfma_f32_16x16x32_bf16(ah1, bl1, a11, 0, 0, 0);
    a00 = __builtin_amdgcn_mfma_f32_16x16x32_bf16(al0, bh0, a00, 0, 0, 0);
    a01 = __builtin_amdgcn_mfma_f32_16x16x32_bf16(al0, bh1, a01, 0, 0, 0);
    a10 = __builtin_amdgcn_mfma_f32_16x16x32_bf16(al1, bh0, a10, 0, 0, 0);
    a11 = __builtin_amdgcn_mfma_f32_16x16x32_bf16(al1, bh1, a11, 0, 0, 0);
  }
  float* pp = part + (size_t)(ks*NCAM + n)*FCc*PIX;
  int ocb = oc0 + ocr + ((lane >> 4) << 2);
  int pxb = px0 + pxr + (lane & 15);
  #pragma unroll
  for (int i = 0; i < 4; ++i) {
    pp[(size_t)(ocb + i)*PIX + pxb]           = a00[i];
    pp[(size_t)(ocb + i)*PIX + pxb + 16]      = a01[i];
    pp[(size_t)(ocb + 16 + i)*PIX + pxb]      = a10[i];
    pp[(size_t)(ocb + 16 + i)*PIX + pxb + 16] = a11[i];
  }
}

// bf16x3 MFMA GEMM for conv3 (1x1, K=128, bias fused, direct X3 write).
__global__ __launch_bounds__(256) void k_gemm_mfma3(
    const float* __restrict__ in, const float* ws,
    const float* __restrict__ bias, float* __restrict__ outbuf)
{
  __shared__ int alds[2][64*LROW];
  __shared__ int blds[2][64*LROW];
  int tid = threadIdx.x;
  int px0 = blockIdx.x * 64;
  int oc0 = blockIdx.y * 64;
  int n = blockIdx.z;
  const unsigned short* whi = (const unsigned short*)(ws + OFF_WT3);
  const unsigned short* wlo = whi + 24576;
  const float* inn = in + (size_t)n*FCc*PIX;
  int wv = tid >> 6, lane = tid & 63;
  int a_oc = tid >> 2, a_kq = tid & 3;
  int b_px = tid & 63, b_kq = tid >> 6;
  int p = px0 + b_px;

  i32x4 pa_h, pa_l; float bvv[8];
  auto issueA = [&](int s) {
    size_t gi = (size_t)(oc0 + a_oc)*128 + (s*32 + a_kq*8);
    pa_h = *(const i32x4*)(whi + gi);
    pa_l = *(const i32x4*)(wlo + gi);
  };
  auto issueB = [&](int s) {
    #pragma unroll
    for (int j = 0; j < 8; ++j) {
      int ic = s*32 + b_kq*8 + j;
      bvv[j] = inn[(size_t)ic*PIX + p];
    }
  };

  f32x4 a00 = {0.f,0.f,0.f,0.f}, a01 = a00, a10 = a00, a11 = a00;
  int ocr = (wv >> 1) * 32, pxr = (wv & 1) * 32;
  int dq = (lane >> 4) * 4;
  int rA0 = (ocr + (lane & 15)) * LROW + dq;
  int rA1 = rA0 + 16*LROW;
  int rB0 = (pxr + (lane & 15)) * LROW + dq;
  int rB1 = rB0 + 16*LROW;
  int aw = a_oc*LROW + a_kq*4;
  int bw = b_px*LROW + b_kq*4;

  issueA(0); issueB(0);
  for (int s = 0; s < 4; ++s) {
    __syncthreads();
    *(i32x4*)&alds[0][aw] = pa_h;
    *(i32x4*)&alds[1][aw] = pa_l;
    {
      i32x4 vh, vl;
      int th[8], tl[8];
      #pragma unroll
      for (int j = 0; j < 8; ++j) {
        unsigned short h = f2bf(bvv[j]);
        th[j] = h; tl[j] = f2bf(bvv[j] - bf2f(h));
      }
      vh.x = th[0]|(th[1]<<16); vh.y = th[2]|(th[3]<<16);
      vh.z = th[4]|(th[5]<<16); vh.w = th[6]|(th[7]<<16);
      vl.x = tl[0]|(tl[1]<<16); vl.y = tl[2]|(tl[3]<<16);
      vl.z = tl[4]|(tl[5]<<16); vl.w = tl[6]|(tl[7]<<16);
      *(i32x4*)&blds[0][bw] = vh;
      *(i32x4*)&blds[1][bw] = vl;
    }
    __syncthreads();
    if (s < 3) { issueA(s+1); issueB(s+1); }
    bf16x8 ah0 = *(bf16x8*)&alds[0][rA0], ah1 = *(bf16x8*)&alds[0][rA1];
    bf16x8 al0 = *(bf16x8*)&alds[1][rA0], al1 = *(bf16x8*)&alds[1][rA1];
    bf16x8 bh0 = *(bf16x8*)&blds[0][rB0], bh1 = *(bf16x8*)&blds[0][rB1];
    bf16x8 bl0 = *(bf16x8*)&blds[1][rB0], bl1 = *(bf16x8*)&blds[1][rB1];
    a00 = __builtin_amdgcn_mfma_f32_16x16x32_bf16(ah0, bh0, a00, 0, 0, 0);
    a01 = __builtin_amdgcn_mfma_f32_16x16x32_bf16(ah0, bh1, a01, 0, 0, 0);
    a10 = __builtin_amdgcn_mfma_f32_16x16x32_bf16(ah1, bh0, a10, 0, 0, 0);
    a11 = __builtin_amdgcn_mfma_f32_16x16x32_bf16(ah1, bh1, a11, 0, 0, 0);
    a00 = __builtin_amdgcn_mfma_f32_16x16x32_bf16(ah0, bl0, a00, 0, 0, 0);
    a01 = __builtin_amdgcn_mfma_f32_16x16x32_bf16(ah0, bl1, a01, 0, 0, 0);
    a10 = __builtin_amdgcn_mfma_f32_16x16x32_bf16(ah1, bl0, a10, 0, 0, 0);
    a11 = __builtin_amdgcn_mfma_f32_16x16x32_bf16(ah1, bl1, a11, 0, 0, 0);
    a00 = __builtin_amdgcn_mfma_f32_16x16x32_bf16(al0, bh0, a00, 0, 0, 0);
    a01 = __builtin_amdgcn_mfma_f32_16x16x32_bf16(al0, bh1, a01, 0, 0, 0);
    a10 = __builtin_amdgcn_mfma_f32_16x16x32_bf16(al1, bh0, a10, 0, 0, 0);
    a11 = __builtin_amdgcn_mfma_f32_16x16x32_bf16(al1, bh1, a11, 0, 0, 0);
  }
  int ocb = oc0 + ocr + ((lane >> 4) << 2);
  int pxb = px0 + pxr + (lane & 15);
  #pragma unroll
  for (int i = 0; i < 4; ++i) {
    int o0 = ocb + i, o1 = ocb + 16 + i;
    if (o0 < C3) {
      float b = bias[o0];
      outbuf[(size_t)(n*C3 + o0)*PIX + pxb]      = a00[i] + b;
      outbuf[(size_t)(n*C3 + o0)*PIX + pxb + 16] = a01[i] + b;
    }
    if (o1 < C3) {
      float b = bias[o1];
      outbuf[(size_t)(n*C3 + o1)*PIX + pxb]      = a10[i] + b;
      outbuf[(size_t)(n*C3 + o1)*PIX + pxb + 16] = a11[i] + b;
    }
  }
}

__global__ void k_epi_bn(const float* __restrict__ part, const float* __restrict__ cb,
                         const float* __restrict__ g, const float* __restrict__ be,
                         const float* __restrict__ mn, const float* __restrict__ vr,
                         float* __restrict__ out, int KSPLIT)
{
  int idx = blockIdx.x*256 + threadIdx.x;
  if (idx >= NCAM*FCc*176) return;
  int px4 = idx % 176;
  int t = idx / 176;
  int oc = t % FCc;
  int n = t / FCc;
  float4 s = {0.f,0.f,0.f,0.f};
  for (int ks = 0; ks < KSPLIT; ++ks) {
    const float4* p = (const float4*)(part + (size_t)((ks*NCAM+n)*FCc + oc)*PIX);
    float4 v = p[px4];
    s.x += v.x; s.y += v.y; s.z += v.z; s.w += v.w;
  }
  float inv = g[oc] * rsqrtf(vr[oc] + 1e-3f);
  float sh = (cb[oc] - mn[oc]) * inv + be[oc];
  float4 o;
  o.x = fmaxf(s.x*inv + sh, 0.f);
  o.y = fmaxf(s.y*inv + sh, 0.f);
  o.z = fmaxf(s.z*inv + sh, 0.f);
  o.w = fmaxf(s.w*inv + sh, 0.f);
  ((float4*)(out + (size_t)(n*FCc + oc)*PIX))[px4] = o;
}

__global__ void k_moments(float* __restrict__ ws) {
  int wid  = (blockIdx.x * 256 + threadIdx.x) >> 6;
  int lane = threadIdx.x & 63;
  int n = wid / PIX, hw = wid % PIX;
  const float* x3 = ws + OFF_X3 + (size_t)n*C3*PIX + hw;
  float logit = (lane < DB) ? x3[(size_t)lane*PIX] : -1e30f;
  float mx = logit;
  for (int off = 1; off < 64; off <<= 1) mx = fmaxf(mx, __shfl_xor(mx, off));
  float e = (lane < DB) ? expf(logit - mx) : 0.f;
  float s = e;
  for (int off = 1; off < 64; off <<= 1) s += __shfl_xor(s, off);
  float p = e / s;
  float gx = 0.f, gy = 0.f;
  if (lane < DB) {
    float2 g2 = ((const float2*)(ws + OFF_GEO))[(size_t)(n*DB + lane)*PIX + hw];
    gx = g2.x; gy = g2.y;
  }
  float sx = p*gx;
  for (int off = 1; off < 64; off <<= 1) sx += __shfl_xor(sx, off);
  float sy = p*gy;
  for (int off = 1; off < 64; off <<= 1) sy += __shfl_xor(sy, off);
  float dx = gx - sx, dy = gy - sy;
  float c00 = p*dx*dx, c01 = p*dx*dy, c11 = p*dy*dy;
  for (int off = 1; off < 64; off <<= 1) c00 += __shfl_xor(c00, off);
  for (int off = 1; off < 64; off <<= 1) c01 += __shfl_xor(c01, off);
  for (int off = 1; off < 64; off <<= 1) c11 += __shfl_xor(c11, off);
  float opl = x3[(size_t)DB*PIX];
  float opac = 1.f / (1.f + expf(-opl));
  float a = c11*(1.f/9.f) + 0.3f;
  float b = c01*(1.f/9.f);
  float c = c00*(1.f/9.f) + 0.3f;
  float py = 50.f - sy;
  float px = 50.f - sx;
  float det = a*c - b*b;
  float op = (opac > 0.05f) ? opac : 0.f;
  float invd = 1.f;
  if (det > 0.f) invd = 1.f/det; else op = 0.f;
  if (lane == 0) {
    float lop = (op > 0.f) ? logf(op) : -1e30f;   // log-space opacity
    ((float4*)(ws + OFF_PRM))[wid]  = make_float4(py, px, -0.5f*c*invd, -0.5f*a*invd);
    ((float2*)(ws + OFF_PRM2))[wid] = make_float2(b*invd, lop);
  }
  float* ft = ws + OFF_FEATT + (size_t)wid*128;
  ft[lane]      = x3[(size_t)(DB + 1 + lane)*PIX];
  ft[lane + 64] = x3[(size_t)(DB + 1 + lane + 64)*PIX];
}

template<int CTRL, int RMASK>
__device__ __forceinline__ float dpp_mul(float v) {
  int t = __builtin_amdgcn_update_dpp(0x3f800000, __float_as_int(v), CTRL, RMASK, 0xF, false);
  return v * __int_as_float(t);
}

// Dense raster (R10 config: linear order, CHUNK=2048, 8-wide batch) + log-space
// early rejection: alpha>=1/255 <=> pw+lop >= -ln255, tested BEFORE exp; the
// exp/clamps run only in hit groups. alpha = min(exp(min(t,lop)), 0.99).
__global__ __launch_bounds__(512) void k_raster(const float* __restrict__ ws,
                                                float* __restrict__ out) {
  __shared__ float4 s4[CHUNK];
  __shared__ float2 s2[CHUNK];
  int lane = threadIdx.x & 63, wv = threadIdx.x >> 6;
  int pix = blockIdx.x * 8 + wv;
  float yi = (float)(pix / 100), xi = (float)(pix % 100);
  const float4* prm4 = (const float4*)(ws + OFF_PRM);
  const float2* prm2 = (const float2*)(ws + OFF_PRM2);
  const float2* ft = (const float2*)(ws + OFF_FEATT);
  float T = 1.f, ax = 0.f, ay = 0.f;
  bool alive = true;
  for (int c0 = 0; c0 < NG; c0 += CHUNK) {
    if (__syncthreads_count(alive ? 1 : 0) == 0) break;
    int cn = min(CHUNK, NG - c0);
    for (int i = threadIdx.x; i < cn; i += 512) {
      s4[i] = prm4[c0 + i];
      s2[i] = prm2[c0 + i];
    }
    __syncthreads();
    if (alive) {
      for (int gl = 0; gl < cn; gl += 64) {
        float4 c4 = s4[gl + lane];
        float2 c2 = s2[gl + lane];
        float dyv = c4.x - yi, dxv = c4.y - xi;
        float pw = c4.z*dyv*dyv + c4.w*dxv*dxv + c2.x*dyv*dxv;
        float t  = pw + c2.y;                       // pw + log(op)
        bool hit = (t >= TH_LOG);
        unsigned long long m0 = __ballot(hit);
        if (m0) {
          float alpha = __expf(fminf(t, c2.y));     // op*exp(min(pw,0))
          alpha = fminf(alpha, 0.99f);
          alpha = hit ? alpha : 0.f;
          float P = 1.f - alpha;
          P = dpp_mul<0x111, 0xF>(P);
          P = dpp_mul<0x112, 0xF>(P);
          P = dpp_mul<0x114, 0xF>(P);
          P = dpp_mul<0x118, 0xF>(P);
          P = dpp_mul<0x142, 0xA>(P);
          P = dpp_mul<0x143, 0xC>(P);
          float E = __int_as_float(__builtin_amdgcn_update_dpp(
                      0x3f800000, __float_as_int(P), 0x138, 0xF, 0xF, false));
          float w = alpha * T * E;
          T *= __int_as_float(__builtin_amdgcn_readlane(__float_as_int(P), 63));
          unsigned long long mask = __ballot(w > 1e-9f);
          int g0 = c0 + gl;
          while (mask) {
            int jj[8];
            #pragma unroll
            for (int b = 0; b < 8; ++b) {
              if (mask) { jj[b] = __builtin_ctzll(mask); mask &= mask - 1ull; }
              else jj[b] = -1;
            }
            float2 fb[8]; float wb[8];
            #pragma unroll
            for (int b = 0; b < 8; ++b) {
              int j = (jj[b] >= 0) ? jj[b] : jj[0];
              fb[b] = ft[(size_t)(g0 + j)*64 + lane];
              wb[b] = (jj[b] >= 0)
                ? __int_as_float(__builtin_amdgcn_readlane(__float_as_int(w), jj[b]))
                : 0.f;
            }
            #pragma unroll
            for (int b = 0; b < 8; ++b) { ax += wb[b]*fb[b].x; ay += wb[b]*fb[b].y; }
          }
          if (T < 1e-7f) { alive = false; break; }
        }
      }
    }
  }
  out[(size_t)(2*lane)*BEVN + pix]   = ax;
  out[(size_t)(2*lane+1)*BEVN + pix] = ay;
}

extern "C" void kernel_launch(void* const* d_in, const int* in_sizes, int n_in,
                              void* d_out, int out_size, void* d_ws, size_t ws_size,
                              hipStream_t stream) {
  const float* rot        = (const float*)d_in[0];
  const float* trans      = (const float*)d_in[1];
  const float* intr       = (const float*)d_in[2];
  const float* post_rot   = (const float*)d_in[3];
  const float* post_trans = (const float*)d_in[4];
  const float* img        = (const float*)d_in[5];
  const float* w1  = (const float*)d_in[6];
  const float* b1  = (const float*)d_in[7];
  const float* g1  = (const float*)d_in[8];
  const float* be1 = (const float*)d_in[9];
  const float* m1  = (const float*)d_in[10];
  const float* v1  = (const float*)d_in[11];
  const float* w2  = (const float*)d_in[12];
  const float* b2  = (const float*)d_in[13];
  const float* g2  = (const float*)d_in[14];
  const float* be2 = (const float*)d_in[15];
  const float* m2  = (const float*)d_in[16];
  const float* v2  = (const float*)d_in[17];
  const float* w3  = (const float*)d_in[18];
  const float* b3  = (const float*)d_in[19];
  float* ws  = (float*)d_ws;
  float* out = (float*)d_out;

  k_wtrans<<<576, 256, 0, stream>>>(w1, w2, w3, ws);
  k_geom<<<792, 256, 0, stream>>>(rot, intr, post_rot, trans, post_trans, ws);

  // conv1: bf16x3 MFMA, K=1152, KSPLIT=4
  k_gemm_mfma<<<dim3(11,2,24), 256, 0, stream>>>(img, ws, ws+OFF_PART, OFF_WT1);
  k_epi_bn<<<528, 256, 0, stream>>>(ws+OFF_PART, b1, g1, be1, m1, v1, ws+OFF_X1, 4);
  // conv2
  k_gemm_mfma<<<dim3(11,2,24), 256, 0, stream>>>(ws+OFF_X1, ws, ws+OFF_PART, OFF_WT2);
  k_epi_bn<<<528, 256, 0, stream>>>(ws+OFF_PART, b2, g2, be2, m2, v2, ws+OFF_X2, 4);
  // conv3: 1x1, K=128, bf16x3 MFMA, bias fused, direct X3 write
  k_gemm_mfma3<<<dim3(11,3,6), 256, 0, stream>>>(ws+OFF_X2, ws, b3, ws+OFF_X3);

  k_moments<<<1056, 256, 0, stream>>>(ws);
  k_raster<<<1250, 512, 0, stream>>>(ws, out);
}

// Round 14
// 123.350 us; speedup vs baseline: 1.1798x; 1.0095x over previous
//
#include <hip/hip_runtime.h>
#include <math.h>

#define NCAM 6
#define FHh 16
#define FWw 44
#define PIX 704            // FHh*FWw
#define FCc 128
#define DB 48
#define C3 177             // DB + 1 + 128
#define C3PAD 192
#define KCONV 1152         // FCc*9
#define NG 4224            // NCAM*PIX
#define BEVN 10000
#define NSPLIT 3
#define SG 1408            // gaussians per split (22 groups of 64)
#define TH_LOG (-5.5412635f)   // -ln(255): alpha>=1/255  <=>  pw+lop >= TH_LOG

// ---- ws layout (float offsets) ----
// Phase A (convs): WT*, GEO, X1, X2, X3, PART
// Phase B (moments): X3+GEO -> PRM/PRM2/FEATT
// Phase C (raster): PRM/PRM2/FEATT + SF/SP partials (alias dead conv buffers)
#define OFF_WT1    0                           // bf16 hi/lo ushorts (147456 floats)
#define OFF_WT2    147456
#define OFF_WT3    294912                      // bf16 hi/lo [192][128] (24576 floats)
#define OFF_GEO    319488                      // [6*48*704][2]
#define OFF_X1     724992                      // [6][128][704]
#define OFF_X2     1265664
#define OFF_X3     1806336                     // [6][177][704]
#define OFF_PART   2553984                     // [4][6][128][704] conv partials
#define OFF_PRM    4716672                     // float4 [NG]: py,px,qc,qa
#define OFF_PRM2   4733568                     // float2 [NG]: qb,lop
#define OFF_FEATT  4742016                     // [NG][128]
#define OFF_SF     0                           // [NSPLIT][BEVN][128] raster partials (aliases convs)
#define OFF_SP     3840000                     // [NSPLIT][BEVN] local transmittance
// end = 5,282,688 floats = 21.1 MiB

typedef __attribute__((ext_vector_type(8))) short bf16x8;
typedef __attribute__((ext_vector_type(4))) float f32x4;
typedef __attribute__((ext_vector_type(4))) int i32x4;

__device__ __forceinline__ unsigned short f2bf(float x) {
  unsigned u = __float_as_uint(x);
  return (unsigned short)((u + 0x7FFF + ((u >> 16) & 1)) >> 16);
}
__device__ __forceinline__ float bf2f(unsigned short h) {
  return __uint_as_float(((unsigned)h) << 16);
}

__device__ __forceinline__ void inv3(const float* A, float* I) {
  float a=A[0],b=A[1],c=A[2],d=A[3],e=A[4],f=A[5],g=A[6],h=A[7],i=A[8];
  float c0 = e*i - f*h, c1 = f*g - d*i, c2 = d*h - e*g;
  float det = a*c0 + b*c1 + c*c2;
  float id = 1.f/det;
  I[0]=c0*id; I[1]=(c*h-b*i)*id; I[2]=(b*f-c*e)*id;
  I[3]=c1*id; I[4]=(a*i-c*g)*id; I[5]=(c*d-a*f)*id;
  I[6]=c2*id; I[7]=(b*g-a*h)*id; I[8]=(a*e-b*d)*id;
}

// fused prep + geometry
__global__ void k_geom(const float* __restrict__ rot, const float* __restrict__ intr,
                       const float* __restrict__ post_rot,
                       const float* __restrict__ trans, const float* __restrict__ post_trans,
                       float* __restrict__ ws) {
  __shared__ float sm[NCAM][24];
  if (threadIdx.x < NCAM) {
    int n = threadIdx.x;
    float ip[9], ii[9];
    inv3(post_rot + n*9, ip);
    inv3(intr + n*9, ii);
    const float* R = rot + n*9;
    for (int j = 0; j < 9; ++j) sm[n][j] = ip[j];
    for (int r = 0; r < 3; ++r)
      for (int c = 0; c < 3; ++c) {
        float s = 0.f;
        for (int k = 0; k < 3; ++k) s += R[r*3+k]*ii[k*3+c];
        sm[n][9 + r*3 + c] = s;
      }
  }
  __syncthreads();
  int idx = blockIdx.x*256 + threadIdx.x;
  if (idx >= NCAM*DB*PIX) return;
  int n = idx / (DB*PIX);
  int rem = idx % (DB*PIX);
  int d = rem / PIX;
  int hw = rem % PIX;
  int h = hw / FWw, w = hw % FWw;
  float fx = w * (351.0f/43.0f);
  float fy = h * (127.0f/15.0f);
  float fz = 1.0f + (float)d;
  const float* pt = post_trans + n*3;
  float v0 = fx - pt[0], v1 = fy - pt[1], v2 = fz - pt[2];
  const float* m = sm[n];
  float x = m[0]*v0 + m[1]*v1 + m[2]*v2;
  float y = m[3]*v0 + m[4]*v1 + m[5]*v2;
  float z = m[6]*v0 + m[7]*v1 + m[8]*v2;
  float q0 = x*z, q1 = y*z, q2 = z;
  const float* c = m + 9;
  const float* t = trans + n*3;
  float gx = c[0]*q0 + c[1]*q1 + c[2]*q2 + t[0];
  float gy = c[3]*q0 + c[4]*q1 + c[5]*q2 + t[1];
  ((float2*)(ws + OFF_GEO))[idx] = make_float2(gx, gy);
}

// all weights -> bf16 hi/lo split, layout [oc][k]
__global__ void k_wtrans(const float* __restrict__ w1, const float* __restrict__ w2,
                         const float* __restrict__ w3, float* __restrict__ ws) {
  int e = blockIdx.x*256 + threadIdx.x;
  if (e < 147456) {
    float v1 = w1[e], v2 = w2[e];
    unsigned short h1 = f2bf(v1), h2 = f2bf(v2);
    unsigned short l1 = f2bf(v1 - bf2f(h1)), l2 = f2bf(v2 - bf2f(h2));
    unsigned short* wt1 = (unsigned short*)(ws + OFF_WT1);
    unsigned short* wt2 = (unsigned short*)(ws + OFF_WT2);
    wt1[e] = h1; wt1[147456 + e] = l1;
    wt2[e] = h2; wt2[147456 + e] = l2;
  }
  if (e < 192*128) {                     // conv3: [oc<192][k<128], zero-pad oc>=177
    int oc = e >> 7, k = e & 127;
    float v = (oc < C3) ? w3[oc*FCc + k] : 0.f;
    unsigned short h = f2bf(v);
    unsigned short* wt3 = (unsigned short*)(ws + OFF_WT3);
    wt3[e] = h; wt3[24576 + e] = f2bf(v - bf2f(h));
  }
}

#define LROW 20   // dwords per LDS row: 32 bf16 = 16 dw + 4 pad

// bf16x3 MFMA im2col GEMM, 3x3 convs. Block 256 thr = 4 waves, 64oc x 64px,
// Kchunk 288 (9 steps of K=32). D = AhBh + AhBl + AlBh.
__global__ __launch_bounds__(256) void k_gemm_mfma(
    const float* __restrict__ in, const float* ws, float* __restrict__ part, int woff)
{
  __shared__ int alds[2][64*LROW];
  __shared__ int blds[2][64*LROW];
  int tid = threadIdx.x;
  int px0 = blockIdx.x * 64;
  int oc0 = blockIdx.y * 64;
  int z = blockIdx.z; int n = z >> 2, ks = z & 3;
  const unsigned short* whi = (const unsigned short*)(ws + woff);
  const unsigned short* wlo = whi + 147456;
  const float* inn = in + (size_t)n*FCc*PIX;
  int wv = tid >> 6, lane = tid & 63;
  int a_oc = tid >> 2, a_kq = tid & 3;
  int b_px = tid & 63, b_kq = tid >> 6;
  int p = px0 + b_px; int b_y = p / FWw, b_x = p - b_y*FWw;
  int k00 = ks * 288;

  i32x4 pa_h, pa_l; float bv[8];
  auto issueA = [&](int s) {
    size_t gi = (size_t)(oc0 + a_oc)*KCONV + (k00 + s*32 + a_kq*8);
    pa_h = *(const i32x4*)(whi + gi);
    pa_l = *(const i32x4*)(wlo + gi);
  };
  auto issueB = [&](int s) {
    #pragma unroll
    for (int j = 0; j < 8; ++j) {
      int k = k00 + s*32 + b_kq*8 + j;
      int ic = k / 9, tap = k - ic*9;
      int ky = tap / 3, kx = tap - ky*3;
      int yy = b_y + ky - 1, xx = b_x + kx - 1;
      float v = 0.f;
      if ((unsigned)yy < FHh && (unsigned)xx < FWw) v = inn[(size_t)ic*PIX + yy*FWw + xx];
      bv[j] = v;
    }
  };

  f32x4 a00 = {0.f,0.f,0.f,0.f}, a01 = a00, a10 = a00, a11 = a00;
  int ocr = (wv >> 1) * 32, pxr = (wv & 1) * 32;
  int dq = (lane >> 4) * 4;
  int rA0 = (ocr + (lane & 15)) * LROW + dq;
  int rA1 = rA0 + 16*LROW;
  int rB0 = (pxr + (lane & 15)) * LROW + dq;
  int rB1 = rB0 + 16*LROW;
  int aw = a_oc*LROW + a_kq*4;
  int bw = b_px*LROW + b_kq*4;

  issueA(0); issueB(0);
  for (int s = 0; s < 9; ++s) {
    __syncthreads();
    *(i32x4*)&alds[0][aw] = pa_h;
    *(i32x4*)&alds[1][aw] = pa_l;
    {
      i32x4 vh, vl;
      int th[8], tl[8];
      #pragma unroll
      for (int j = 0; j < 8; ++j) {
        unsigned short h = f2bf(bv[j]);
        th[j] = h; tl[j] = f2bf(bv[j] - bf2f(h));
      }
      vh.x = th[0]|(th[1]<<16); vh.y = th[2]|(th[3]<<16);
      vh.z = th[4]|(th[5]<<16); vh.w = th[6]|(th[7]<<16);
      vl.x = tl[0]|(tl[1]<<16); vl.y = tl[2]|(tl[3]<<16);
      vl.z = tl[4]|(tl[5]<<16); vl.w = tl[6]|(tl[7]<<16);
      *(i32x4*)&blds[0][bw] = vh;
      *(i32x4*)&blds[1][bw] = vl;
    }
    __syncthreads();
    if (s < 8) { issueA(s+1); issueB(s+1); }
    bf16x8 ah0 = *(bf16x8*)&alds[0][rA0], ah1 = *(bf16x8*)&alds[0][rA1];
    bf16x8 al0 = *(bf16x8*)&alds[1][rA0], al1 = *(bf16x8*)&alds[1][rA1];
    bf16x8 bh0 = *(bf16x8*)&blds[0][rB0], bh1 = *(bf16x8*)&blds[0][rB1];
    bf16x8 bl0 = *(bf16x8*)&blds[1][rB0], bl1 = *(bf16x8*)&blds[1][rB1];
    a00 = __builtin_amdgcn_mfma_f32_16x16x32_bf16(ah0, bh0, a00, 0, 0, 0);
    a01 = __builtin_amdgcn_mfma_f32_16x16x32_bf16(ah0, bh1, a01, 0, 0, 0);
    a10 = __builtin_amdgcn_mfma_f32_16x16x32_bf16(ah1, bh0, a10, 0, 0, 0);
    a11 = __builtin_amdgcn_mfma_f32_16x16x32_bf16(ah1, bh1, a11, 0, 0, 0);
    a00 = __builtin_amdgcn_mfma_f32_16x16x32_bf16(ah0, bl0, a00, 0, 0, 0);
    a01 = __builtin_amdgcn_mfma_f32_16x16x32_bf16(ah0, bl1, a01, 0, 0, 0);
    a10 = __builtin_amdgcn_mfma_f32_16x16x32_bf16(ah1, bl0, a10, 0, 0, 0);
    a11 = __builtin_amdgcn_mfma_f32_16x16x32_bf16(ah1, bl1, a11, 0, 0, 0);
    a00 = __builtin_amdgcn_mfma_f32_16x16x32_bf16(al0, bh0, a00, 0, 0, 0);
    a01 = __builtin_amdgcn_mfma_f32_16x16x32_bf16(al0, bh1, a01, 0, 0, 0);
    a10 = __builtin_amdgcn_mfma_f32_16x16x32_bf16(al1, bh0, a10, 0, 0, 0);
    a11 = __builtin_amdgcn_mfma_f32_16x16x32_bf16(al1, bh1, a11, 0, 0, 0);
  }
  float* pp = part + (size_t)(ks*NCAM + n)*FCc*PIX;
  int ocb = oc0 + ocr + ((lane >> 4) << 2);
  int pxb = px0 + pxr + (lane & 15);
  #pragma unroll
  for (int i = 0; i < 4; ++i) {
    pp[(size_t)(ocb + i)*PIX + pxb]           = a00[i];
    pp[(size_t)(ocb + i)*PIX + pxb + 16]      = a01[i];
    pp[(size_t)(ocb + 16 + i)*PIX + pxb]      = a10[i];
    pp[(size_t)(ocb + 16 + i)*PIX + pxb + 16] = a11[i];
  }
}

// bf16x3 MFMA GEMM for conv3 (1x1, K=128, bias fused, direct X3 write).
__global__ __launch_bounds__(256) void k_gemm_mfma3(
    const float* __restrict__ in, const float* ws,
    const float* __restrict__ bias, float* __restrict__ outbuf)
{
  __shared__ int alds[2][64*LROW];
  __shared__ int blds[2][64*LROW];
  int tid = threadIdx.x;
  int px0 = blockIdx.x * 64;
  int oc0 = blockIdx.y * 64;
  int n = blockIdx.z;
  const unsigned short* whi = (const unsigned short*)(ws + OFF_WT3);
  const unsigned short* wlo = whi + 24576;
  const float* inn = in + (size_t)n*FCc*PIX;
  int wv = tid >> 6, lane = tid & 63;
  int a_oc = tid >> 2, a_kq = tid & 3;
  int b_px = tid & 63, b_kq = tid >> 6;
  int p = px0 + b_px;

  i32x4 pa_h, pa_l; float bvv[8];
  auto issueA = [&](int s) {
    size_t gi = (size_t)(oc0 + a_oc)*128 + (s*32 + a_kq*8);
    pa_h = *(const i32x4*)(whi + gi);
    pa_l = *(const i32x4*)(wlo + gi);
  };
  auto issueB = [&](int s) {
    #pragma unroll
    for (int j = 0; j < 8; ++j) {
      int ic = s*32 + b_kq*8 + j;
      bvv[j] = inn[(size_t)ic*PIX + p];
    }
  };

  f32x4 a00 = {0.f,0.f,0.f,0.f}, a01 = a00, a10 = a00, a11 = a00;
  int ocr = (wv >> 1) * 32, pxr = (wv & 1) * 32;
  int dq = (lane >> 4) * 4;
  int rA0 = (ocr + (lane & 15)) * LROW + dq;
  int rA1 = rA0 + 16*LROW;
  int rB0 = (pxr + (lane & 15)) * LROW + dq;
  int rB1 = rB0 + 16*LROW;
  int aw = a_oc*LROW + a_kq*4;
  int bw = b_px*LROW + b_kq*4;

  issueA(0); issueB(0);
  for (int s = 0; s < 4; ++s) {
    __syncthreads();
    *(i32x4*)&alds[0][aw] = pa_h;
    *(i32x4*)&alds[1][aw] = pa_l;
    {
      i32x4 vh, vl;
      int th[8], tl[8];
      #pragma unroll
      for (int j = 0; j < 8; ++j) {
        unsigned short h = f2bf(bvv[j]);
        th[j] = h; tl[j] = f2bf(bvv[j] - bf2f(h));
      }
      vh.x = th[0]|(th[1]<<16); vh.y = th[2]|(th[3]<<16);
      vh.z = th[4]|(th[5]<<16); vh.w = th[6]|(th[7]<<16);
      vl.x = tl[0]|(tl[1]<<16); vl.y = tl[2]|(tl[3]<<16);
      vl.z = tl[4]|(tl[5]<<16); vl.w = tl[6]|(tl[7]<<16);
      *(i32x4*)&blds[0][bw] = vh;
      *(i32x4*)&blds[1][bw] = vl;
    }
    __syncthreads();
    if (s < 3) { issueA(s+1); issueB(s+1); }
    bf16x8 ah0 = *(bf16x8*)&alds[0][rA0], ah1 = *(bf16x8*)&alds[0][rA1];
    bf16x8 al0 = *(bf16x8*)&alds[1][rA0], al1 = *(bf16x8*)&alds[1][rA1];
    bf16x8 bh0 = *(bf16x8*)&blds[0][rB0], bh1 = *(bf16x8*)&blds[0][rB1];
    bf16x8 bl0 = *(bf16x8*)&blds[1][rB0], bl1 = *(bf16x8*)&blds[1][rB1];
    a00 = __builtin_amdgcn_mfma_f32_16x16x32_bf16(ah0, bh0, a00, 0, 0, 0);
    a01 = __builtin_amdgcn_mfma_f32_16x16x32_bf16(ah0, bh1, a01, 0, 0, 0);
    a10 = __builtin_amdgcn_mfma_f32_16x16x32_bf16(ah1, bh0, a10, 0, 0, 0);
    a11 = __builtin_amdgcn_mfma_f32_16x16x32_bf16(ah1, bh1, a11, 0, 0, 0);
    a00 = __builtin_amdgcn_mfma_f32_16x16x32_bf16(ah0, bl0, a00, 0, 0, 0);
    a01 = __builtin_amdgcn_mfma_f32_16x16x32_bf16(ah0, bl1, a01, 0, 0, 0);
    a10 = __builtin_amdgcn_mfma_f32_16x16x32_bf16(ah1, bl0, a10, 0, 0, 0);
    a11 = __builtin_amdgcn_mfma_f32_16x16x32_bf16(ah1, bl1, a11, 0, 0, 0);
    a00 = __builtin_amdgcn_mfma_f32_16x16x32_bf16(al0, bh0, a00, 0, 0, 0);
    a01 = __builtin_amdgcn_mfma_f32_16x16x32_bf16(al0, bh1, a01, 0, 0, 0);
    a10 = __builtin_amdgcn_mfma_f32_16x16x32_bf16(al1, bh0, a10, 0, 0, 0);
    a11 = __builtin_amdgcn_mfma_f32_16x16x32_bf16(al1, bh1, a11, 0, 0, 0);
  }
  int ocb = oc0 + ocr + ((lane >> 4) << 2);
  int pxb = px0 + pxr + (lane & 15);
  #pragma unroll
  for (int i = 0; i < 4; ++i) {
    int o0 = ocb + i, o1 = ocb + 16 + i;
    if (o0 < C3) {
      float b = bias[o0];
      outbuf[(size_t)(n*C3 + o0)*PIX + pxb]      = a00[i] + b;
      outbuf[(size_t)(n*C3 + o0)*PIX + pxb + 16] = a01[i] + b;
    }
    if (o1 < C3) {
      float b = bias[o1];
      outbuf[(size_t)(n*C3 + o1)*PIX + pxb]      = a10[i] + b;
      outbuf[(size_t)(n*C3 + o1)*PIX + pxb + 16] = a11[i] + b;
    }
  }
}

__global__ void k_epi_bn(const float* __restrict__ part, const float* __restrict__ cb,
                         const float* __restrict__ g, const float* __restrict__ be,
                         const float* __restrict__ mn, const float* __restrict__ vr,
                         float* __restrict__ out, int KSPLIT)
{
  int idx = blockIdx.x*256 + threadIdx.x;
  if (idx >= NCAM*FCc*176) return;
  int px4 = idx % 176;
  int t = idx / 176;
  int oc = t % FCc;
  int n = t / FCc;
  float4 s = {0.f,0.f,0.f,0.f};
  for (int ks = 0; ks < KSPLIT; ++ks) {
    const float4* p = (const float4*)(part + (size_t)((ks*NCAM+n)*FCc + oc)*PIX);
    float4 v = p[px4];
    s.x += v.x; s.y += v.y; s.z += v.z; s.w += v.w;
  }
  float inv = g[oc] * rsqrtf(vr[oc] + 1e-3f);
  float sh = (cb[oc] - mn[oc]) * inv + be[oc];
  float4 o;
  o.x = fmaxf(s.x*inv + sh, 0.f);
  o.y = fmaxf(s.y*inv + sh, 0.f);
  o.z = fmaxf(s.z*inv + sh, 0.f);
  o.w = fmaxf(s.w*inv + sh, 0.f);
  ((float4*)(out + (size_t)(n*FCc + oc)*PIX))[px4] = o;
}

__global__ void k_moments(float* __restrict__ ws) {
  int wid  = (blockIdx.x * 256 + threadIdx.x) >> 6;
  int lane = threadIdx.x & 63;
  int n = wid / PIX, hw = wid % PIX;
  const float* x3 = ws + OFF_X3 + (size_t)n*C3*PIX + hw;
  float logit = (lane < DB) ? x3[(size_t)lane*PIX] : -1e30f;
  float mx = logit;
  for (int off = 1; off < 64; off <<= 1) mx = fmaxf(mx, __shfl_xor(mx, off));
  float e = (lane < DB) ? expf(logit - mx) : 0.f;
  float s = e;
  for (int off = 1; off < 64; off <<= 1) s += __shfl_xor(s, off);
  float p = e / s;
  float gx = 0.f, gy = 0.f;
  if (lane < DB) {
    float2 g2 = ((const float2*)(ws + OFF_GEO))[(size_t)(n*DB + lane)*PIX + hw];
    gx = g2.x; gy = g2.y;
  }
  float sx = p*gx;
  for (int off = 1; off < 64; off <<= 1) sx += __shfl_xor(sx, off);
  float sy = p*gy;
  for (int off = 1; off < 64; off <<= 1) sy += __shfl_xor(sy, off);
  float dx = gx - sx, dy = gy - sy;
  float c00 = p*dx*dx, c01 = p*dx*dy, c11 = p*dy*dy;
  for (int off = 1; off < 64; off <<= 1) c00 += __shfl_xor(c00, off);
  for (int off = 1; off < 64; off <<= 1) c01 += __shfl_xor(c01, off);
  for (int off = 1; off < 64; off <<= 1) c11 += __shfl_xor(c11, off);
  float opl = x3[(size_t)DB*PIX];
  float opac = 1.f / (1.f + expf(-opl));
  float a = c11*(1.f/9.f) + 0.3f;
  float b = c01*(1.f/9.f);
  float c = c00*(1.f/9.f) + 0.3f;
  float py = 50.f - sy;
  float px = 50.f - sx;
  float det = a*c - b*b;
  float op = (opac > 0.05f) ? opac : 0.f;
  float invd = 1.f;
  if (det > 0.f) invd = 1.f/det; else op = 0.f;
  if (lane == 0) {
    float lop = (op > 0.f) ? logf(op) : -1e30f;   // log-space opacity
    ((float4*)(ws + OFF_PRM))[wid]  = make_float4(py, px, -0.5f*c*invd, -0.5f*a*invd);
    ((float2*)(ws + OFF_PRM2))[wid] = make_float2(b*invd, lop);
  }
  float* ft = ws + OFF_FEATT + (size_t)wid*128;
  ft[lane]      = x3[(size_t)(DB + 1 + lane)*PIX];
  ft[lane + 64] = x3[(size_t)(DB + 1 + lane + 64)*PIX];
}

template<int CTRL, int RMASK>
__device__ __forceinline__ float dpp_mul(float v) {
  int t = __builtin_amdgcn_update_dpp(0x3f800000, __float_as_int(v), CTRL, RMASK, 0xF, false);
  return v * __int_as_float(t);
}

// Split-K raster: block = 8 pixels x 1 split of 1408 gaussians (22 groups).
// Uniform work per block -> no straggler tail. Single 33.8KB LDS stage (no
// chunk loop). Same inner loop as R13 (log-reject + DPP scan + 8-wide gather).
// Writes partial F[128]/px + local transmittance P; k_combine composes
// F = F0 + P0*F1 + P0*P1*F2 (ordered; reassociation error ~1ulp).
__global__ __launch_bounds__(512) void k_raster(const float* __restrict__ ws,
                                                float* __restrict__ wsout) {
  __shared__ float4 s4[SG];
  __shared__ float2 s2[SG];
  int lane = threadIdx.x & 63, wv = threadIdx.x >> 6;
  int split = blockIdx.x / 1250;
  int pxb   = blockIdx.x % 1250;
  int pix = pxb * 8 + wv;
  float yi = (float)(pix / 100), xi = (float)(pix % 100);
  int gbase = split * SG;
  const float4* prm4 = (const float4*)(ws + OFF_PRM) + gbase;
  const float2* prm2 = (const float2*)(ws + OFF_PRM2) + gbase;
  const float2* ft = (const float2*)(ws + OFF_FEATT);
  for (int i = threadIdx.x; i < SG; i += 512) {
    s4[i] = prm4[i];
    s2[i] = prm2[i];
  }
  __syncthreads();
  float T = 1.f, ax = 0.f, ay = 0.f;
  for (int gl = 0; gl < SG; gl += 64) {
    float4 c4 = s4[gl + lane];
    float2 c2 = s2[gl + lane];
    float dyv = c4.x - yi, dxv = c4.y - xi;
    float pw = c4.z*dyv*dyv + c4.w*dxv*dxv + c2.x*dyv*dxv;
    float t  = pw + c2.y;                       // pw + log(op)
    bool hit = (t >= TH_LOG);
    unsigned long long m0 = __ballot(hit);
    if (m0) {
      float alpha = __expf(fminf(t, c2.y));     // op*exp(min(pw,0))
      alpha = fminf(alpha, 0.99f);
      alpha = hit ? alpha : 0.f;
      float P = 1.f - alpha;
      P = dpp_mul<0x111, 0xF>(P);
      P = dpp_mul<0x112, 0xF>(P);
      P = dpp_mul<0x114, 0xF>(P);
      P = dpp_mul<0x118, 0xF>(P);
      P = dpp_mul<0x142, 0xA>(P);
      P = dpp_mul<0x143, 0xC>(P);
      float E = __int_as_float(__builtin_amdgcn_update_dpp(
                  0x3f800000, __float_as_int(P), 0x138, 0xF, 0xF, false));
      float w = alpha * T * E;
      T *= __int_as_float(__builtin_amdgcn_readlane(__float_as_int(P), 63));
      unsigned long long mask = __ballot(w > 1e-9f);
      int g0 = gbase + gl;
      while (mask) {
        int jj[8];
        #pragma unroll
        for (int b = 0; b < 8; ++b) {
          if (mask) { jj[b] = __builtin_ctzll(mask); mask &= mask - 1ull; }
          else jj[b] = -1;
        }
        float2 fb[8]; float wb[8];
        #pragma unroll
        for (int b = 0; b < 8; ++b) {
          int j = (jj[b] >= 0) ? jj[b] : jj[0];
          fb[b] = ft[(size_t)(g0 + j)*64 + lane];
          wb[b] = (jj[b] >= 0)
            ? __int_as_float(__builtin_amdgcn_readlane(__float_as_int(w), jj[b]))
            : 0.f;
        }
        #pragma unroll
        for (int b = 0; b < 8; ++b) { ax += wb[b]*fb[b].x; ay += wb[b]*fb[b].y; }
      }
      if (T < 1e-7f) break;                     // local exit (error < 1e-7)
    }
  }
  float* sf = wsout + OFF_SF + ((size_t)split*BEVN + pix)*128;
  sf[2*lane]   = ax;
  sf[2*lane+1] = ay;
  if (lane == 0) (wsout + OFF_SP)[split*BEVN + pix] = T;
}

// ordered combine: F = F0 + P0*F1 + P0*P1*F2
__global__ __launch_bounds__(512) void k_combine(const float* __restrict__ ws,
                                                 float* __restrict__ out) {
  int lane = threadIdx.x & 63, wv = threadIdx.x >> 6;
  int pix = blockIdx.x * 8 + wv;
  const float* sp = ws + OFF_SP;
  float P0 = sp[pix], P1 = sp[BEVN + pix];
  const float2* f0 = (const float2*)(ws + OFF_SF + (size_t)pix*128);
  const float2* f1 = (const float2*)(ws + OFF_SF + ((size_t)BEVN + pix)*128);
  const float2* f2 = (const float2*)(ws + OFF_SF + ((size_t)2*BEVN + pix)*128);
  float2 a = f0[lane], b = f1[lane], c = f2[lane];
  float w1 = P0, w2 = P0*P1;
  float ox = a.x + w1*b.x + w2*c.x;
  float oy = a.y + w1*b.y + w2*c.y;
  out[(size_t)(2*lane)*BEVN + pix]   = ox;
  out[(size_t)(2*lane+1)*BEVN + pix] = oy;
}

extern "C" void kernel_launch(void* const* d_in, const int* in_sizes, int n_in,
                              void* d_out, int out_size, void* d_ws, size_t ws_size,
                              hipStream_t stream) {
  const float* rot        = (const float*)d_in[0];
  const float* trans      = (const float*)d_in[1];
  const float* intr       = (const float*)d_in[2];
  const float* post_rot   = (const float*)d_in[3];
  const float* post_trans = (const float*)d_in[4];
  const float* img        = (const float*)d_in[5];
  const float* w1  = (const float*)d_in[6];
  const float* b1  = (const float*)d_in[7];
  const float* g1  = (const float*)d_in[8];
  const float* be1 = (const float*)d_in[9];
  const float* m1  = (const float*)d_in[10];
  const float* v1  = (const float*)d_in[11];
  const float* w2  = (const float*)d_in[12];
  const float* b2  = (const float*)d_in[13];
  const float* g2  = (const float*)d_in[14];
  const float* be2 = (const float*)d_in[15];
  const float* m2  = (const float*)d_in[16];
  const float* v2  = (const float*)d_in[17];
  const float* w3  = (const float*)d_in[18];
  const float* b3  = (const float*)d_in[19];
  float* ws  = (float*)d_ws;
  float* out = (float*)d_out;

  k_wtrans<<<576, 256, 0, stream>>>(w1, w2, w3, ws);
  k_geom<<<792, 256, 0, stream>>>(rot, intr, post_rot, trans, post_trans, ws);

  // conv1: bf16x3 MFMA, K=1152, KSPLIT=4
  k_gemm_mfma<<<dim3(11,2,24), 256, 0, stream>>>(img, ws, ws+OFF_PART, OFF_WT1);
  k_epi_bn<<<528, 256, 0, stream>>>(ws+OFF_PART, b1, g1, be1, m1, v1, ws+OFF_X1, 4);
  // conv2
  k_gemm_mfma<<<dim3(11,2,24), 256, 0, stream>>>(ws+OFF_X1, ws, ws+OFF_PART, OFF_WT2);
  k_epi_bn<<<528, 256, 0, stream>>>(ws+OFF_PART, b2, g2, be2, m2, v2, ws+OFF_X2, 4);
  // conv3: 1x1, K=128, bf16x3 MFMA, bias fused, direct X3 write
  k_gemm_mfma3<<<dim3(11,3,6), 256, 0, stream>>>(ws+OFF_X2, ws, b3, ws+OFF_X3);

  k_moments<<<1056, 256, 0, stream>>>(ws);
  k_raster<<<3750, 512, 0, stream>>>(ws, ws);
  k_combine<<<1250, 512, 0, stream>>>(ws, out);
}